// Round 3
// baseline (263.954 us; speedup 1.0000x reference)
//
#include <hip/hip_runtime.h>
#include <cstdint>

#define NTOK 4096
#define DMODEL 1024

typedef __bf16 bf16x8 __attribute__((ext_vector_type(8)));
typedef float f32x4 __attribute__((ext_vector_type(4)));

__device__ __forceinline__ unsigned short f32_to_bf16(float f) {
    unsigned int u = __float_as_uint(f);
    unsigned int r = 0x7FFFu + ((u >> 16) & 1u);
    return (unsigned short)((u + r) >> 16);
}

// ---------------- fp32 -> bf16 cast (vectorized) ----------------
__global__ __launch_bounds__(256) void cvt_f32_bf16(const float* __restrict__ in,
                                                    unsigned short* __restrict__ out,
                                                    int n4) {
    int i = blockIdx.x * 256 + threadIdx.x;
    if (i >= n4) return;
    float4 v = reinterpret_cast<const float4*>(in)[i];
    ushort4 o;
    o.x = f32_to_bf16(v.x);
    o.y = f32_to_bf16(v.y);
    o.z = f32_to_bf16(v.z);
    o.w = f32_to_bf16(v.w);
    reinterpret_cast<ushort4*>(out)[i] = o;
}

// ---------------- NT bf16 GEMM: C[M,N] = A[M,K] * B[N,K]^T ----------------
// m97 structure: 128x128 tile, BK=64, 4 waves (2x2), 16x16x32 bf16 MFMA,
// global_load_lds width 16, XOR-swizzled LDS (inverse-swizzle on global src,
// swizzle on ds_read; LDS dest stays linear -- guide rule #21).
#define BM 128
#define BN 128
#define BK 64

#define EPI_F32 0
#define EPI_BF16 1
#define EPI_BF16T 2

template <int EPI>
__global__ __launch_bounds__(256, 2) void gemm_nt(
    const unsigned short* __restrict__ A, const unsigned short* __restrict__ B,
    void* __restrict__ C, int K, int lda, int ldb, int ldc) {
    __shared__ __align__(16) unsigned short As[BM * BK];
    __shared__ __align__(16) unsigned short Bs[BN * BK];

    const int tid = threadIdx.x;
    const int lane = tid & 63;
    const int wave = tid >> 6;
    const int wr = wave >> 1, wc = wave & 1;

    const unsigned short* Ablk = A + (size_t)blockIdx.y * BM * lda;
    const unsigned short* Bblk = B + (size_t)blockIdx.x * BN * ldb;

    f32x4 acc[4][4] = {};

    for (int k0 = 0; k0 < K; k0 += BK) {
        // stage 128x64 bf16 tiles of A and B into LDS.
        // chunk c (16B) -> lds bytes [c*16, c*16+16); row = c>>3, phys col-chunk j = c&7
        // holds logical k-chunk jl = j ^ (row&7)  (involution; read applies same XOR)
#pragma unroll
        for (int i = 0; i < 4; ++i) {
            const int c = tid + i * 256;
            const int row = c >> 3;
            const int jl = (c & 7) ^ (row & 7);
            const unsigned short* ga = Ablk + (size_t)row * lda + (k0 + jl * 8);
            const unsigned short* gb = Bblk + (size_t)row * ldb + (k0 + jl * 8);
            __builtin_amdgcn_global_load_lds(
                (const __attribute__((address_space(1))) void*)ga,
                (__attribute__((address_space(3))) void*)(&As[c * 8]), 16, 0, 0);
            __builtin_amdgcn_global_load_lds(
                (const __attribute__((address_space(1))) void*)gb,
                (__attribute__((address_space(3))) void*)(&Bs[c * 8]), 16, 0, 0);
        }
        __syncthreads();  // compiler emits vmcnt(0) drain before the barrier

#pragma unroll
        for (int ks = 0; ks < 2; ++ks) {
            bf16x8 af[4], bfr[4];
#pragma unroll
            for (int m = 0; m < 4; ++m) {
                const int row = wr * 64 + m * 16 + (lane & 15);
                const int ch = (ks * 4 + (lane >> 4)) ^ (row & 7);
                af[m] = *reinterpret_cast<const bf16x8*>(
                    reinterpret_cast<const char*>(As) + row * 128 + ch * 16);
            }
#pragma unroll
            for (int n = 0; n < 4; ++n) {
                const int row = wc * 64 + n * 16 + (lane & 15);
                const int ch = (ks * 4 + (lane >> 4)) ^ (row & 7);
                bfr[n] = *reinterpret_cast<const bf16x8*>(
                    reinterpret_cast<const char*>(Bs) + row * 128 + ch * 16);
            }
#pragma unroll
            for (int m = 0; m < 4; ++m)
#pragma unroll
                for (int n = 0; n < 4; ++n)
                    acc[m][n] = __builtin_amdgcn_mfma_f32_16x16x32_bf16(
                        af[m], bfr[n], acc[m][n], 0, 0, 0);
        }
        __syncthreads();
    }

    // C/D layout (m89/m91 verified): col = lane&15, row = (lane>>4)*4 + r
    const int col0 = blockIdx.x * BN + wc * 64 + (lane & 15);
    const int row0 = blockIdx.y * BM + wr * 64 + ((lane >> 4) << 2);

    if (EPI == EPI_F32) {
        float* Cf = reinterpret_cast<float*>(C);
#pragma unroll
        for (int m = 0; m < 4; ++m)
#pragma unroll
            for (int n = 0; n < 4; ++n)
#pragma unroll
                for (int r = 0; r < 4; ++r)
                    Cf[(size_t)(row0 + m * 16 + r) * ldc + (col0 + n * 16)] = acc[m][n][r];
    } else if (EPI == EPI_BF16) {
        unsigned short* Cb = reinterpret_cast<unsigned short*>(C);
#pragma unroll
        for (int m = 0; m < 4; ++m)
#pragma unroll
            for (int n = 0; n < 4; ++n)
#pragma unroll
                for (int r = 0; r < 4; ++r)
                    Cb[(size_t)(row0 + m * 16 + r) * ldc + (col0 + n * 16)] =
                        f32_to_bf16(acc[m][n][r]);
    } else {  // EPI_BF16T: C[col][row] (used to store V transposed)
        unsigned short* Cb = reinterpret_cast<unsigned short*>(C);
#pragma unroll
        for (int m = 0; m < 4; ++m)
#pragma unroll
            for (int n = 0; n < 4; ++n) {
                ushort4 o;
                o.x = f32_to_bf16(acc[m][n][0]);
                o.y = f32_to_bf16(acc[m][n][1]);
                o.z = f32_to_bf16(acc[m][n][2]);
                o.w = f32_to_bf16(acc[m][n][3]);
                *reinterpret_cast<ushort4*>(
                    &Cb[(size_t)(col0 + n * 16) * ldc + (row0 + m * 16)]) = o;
            }
    }
}

// ---------------- row softmax: P = softmax(S/32), bf16, in-place ----------------
// One block per row. Reads 4096 fp32, writes 4096 bf16 over the FIRST HALF of the
// same row (safe: all global loads drain at the first __syncthreads before stores).
__global__ __launch_bounds__(256) void softmax_rows(float* __restrict__ S, int N) {
    const int row = blockIdx.x;
    float* s = S + (size_t)row * N;
    const int t = threadIdx.x;

    float v[16];
    float mx = -1e30f;
#pragma unroll
    for (int i = 0; i < 4; ++i) {
        float4 x = reinterpret_cast<const float4*>(s)[t + i * 256];
        v[i * 4 + 0] = x.x;
        v[i * 4 + 1] = x.y;
        v[i * 4 + 2] = x.z;
        v[i * 4 + 3] = x.w;
        mx = fmaxf(mx, fmaxf(fmaxf(x.x, x.y), fmaxf(x.z, x.w)));
    }
#pragma unroll
    for (int off = 32; off; off >>= 1) mx = fmaxf(mx, __shfl_xor(mx, off));
    __shared__ float redm[4];
    if (!(t & 63)) redm[t >> 6] = mx;
    __syncthreads();
    mx = fmaxf(fmaxf(redm[0], redm[1]), fmaxf(redm[2], redm[3]));

    float sum = 0.f;
#pragma unroll
    for (int i = 0; i < 16; ++i) {
        v[i] = __expf((v[i] - mx) * 0.03125f);  // softmax(S/32)
        sum += v[i];
    }
#pragma unroll
    for (int off = 32; off; off >>= 1) sum += __shfl_xor(sum, off);
    __shared__ float reds[4];
    if (!(t & 63)) reds[t >> 6] = sum;
    __syncthreads();
    sum = (reds[0] + reds[1]) + (reds[2] + reds[3]);
    const float inv = 1.0f / sum;

    unsigned short* p = reinterpret_cast<unsigned short*>(s);
#pragma unroll
    for (int i = 0; i < 4; ++i) {
        ushort4 o;
        o.x = f32_to_bf16(v[i * 4 + 0] * inv);
        o.y = f32_to_bf16(v[i * 4 + 1] * inv);
        o.z = f32_to_bf16(v[i * 4 + 2] * inv);
        o.w = f32_to_bf16(v[i * 4 + 3] * inv);
        reinterpret_cast<ushort4*>(p)[t + i * 256] = o;
    }
}

extern "C" void kernel_launch(void* const* d_in, const int* in_sizes, int n_in,
                              void* d_out, int out_size, void* d_ws, size_t ws_size,
                              hipStream_t stream) {
    (void)in_sizes; (void)n_in; (void)out_size; (void)ws_size;
    const float* x = (const float*)d_in[0];
    const float* wq = (const float*)d_in[1];
    const float* wk = (const float*)d_in[2];
    const float* wv = (const float*)d_in[3];
    float* out = (float*)d_out;

    // ws layout (MiB offsets): xb 0..8, wqb 8..10, wkb 10..12, wvb 12..14,
    // Qb 14..22, Kb 22..30, Vt 30..38, S 38..102 (P bf16 written in-place over S)
    const size_t MB = 1ull << 20;
    char* w = (char*)d_ws;
    unsigned short* xb  = (unsigned short*)(w + 0 * MB);
    unsigned short* wqb = (unsigned short*)(w + 8 * MB);
    unsigned short* wkb = (unsigned short*)(w + 10 * MB);
    unsigned short* wvb = (unsigned short*)(w + 12 * MB);
    unsigned short* Qb  = (unsigned short*)(w + 14 * MB);
    unsigned short* Kb  = (unsigned short*)(w + 22 * MB);
    unsigned short* Vt  = (unsigned short*)(w + 30 * MB);
    float* S            = (float*)(w + 38 * MB);

    cvt_f32_bf16<<<4096, 256, 0, stream>>>(x, xb, (NTOK * DMODEL) / 4);
    cvt_f32_bf16<<<1024, 256, 0, stream>>>(wq, wqb, (DMODEL * DMODEL) / 4);
    cvt_f32_bf16<<<1024, 256, 0, stream>>>(wk, wkb, (DMODEL * DMODEL) / 4);
    cvt_f32_bf16<<<1024, 256, 0, stream>>>(wv, wvb, (DMODEL * DMODEL) / 4);

    dim3 gqkv(DMODEL / BN, NTOK / BM);  // (8, 32)
    gemm_nt<EPI_BF16><<<gqkv, 256, 0, stream>>>(xb, wqb, Qb, DMODEL, DMODEL, DMODEL, DMODEL);
    gemm_nt<EPI_BF16><<<gqkv, 256, 0, stream>>>(xb, wkb, Kb, DMODEL, DMODEL, DMODEL, DMODEL);
    gemm_nt<EPI_BF16T><<<gqkv, 256, 0, stream>>>(xb, wvb, Vt, DMODEL, DMODEL, DMODEL, NTOK);

    dim3 gs(NTOK / BN, NTOK / BM);  // (32, 32)
    gemm_nt<EPI_F32><<<gs, 256, 0, stream>>>(Qb, Kb, S, DMODEL, DMODEL, DMODEL, NTOK);

    softmax_rows<<<NTOK, 256, 0, stream>>>(S, NTOK);

    // PV: A = P (bf16, row stride 8192 elems = fp32 row reinterpreted), B = Vt
    dim3 gpv(DMODEL / BN, NTOK / BM);  // (8, 32)
    gemm_nt<EPI_F32><<<gpv, 256, 0, stream>>>((const unsigned short*)S, Vt, out,
                                              NTOK, 2 * NTOK, NTOK, DMODEL);
}

// Round 8
// 251.381 us; speedup vs baseline: 1.0500x; 1.0500x over previous
//
#include <hip/hip_runtime.h>
#include <cstdint>

#define NTOK 4096
#define DMODEL 1024

typedef __bf16 bf16x8 __attribute__((ext_vector_type(8)));
typedef float f32x4 __attribute__((ext_vector_type(4)));

__device__ __forceinline__ unsigned short f32_to_bf16(float f) {
    unsigned int u = __float_as_uint(f);
    unsigned int r = 0x7FFFu + ((u >> 16) & 1u);
    return (unsigned short)((u + r) >> 16);
}

// ---------------- fp32 -> bf16 cast (vectorized) ----------------
__global__ __launch_bounds__(256) void cvt_f32_bf16(const float* __restrict__ in,
                                                    unsigned short* __restrict__ out,
                                                    int n4) {
    int i = blockIdx.x * 256 + threadIdx.x;
    if (i >= n4) return;
    float4 v = reinterpret_cast<const float4*>(in)[i];
    ushort4 o;
    o.x = f32_to_bf16(v.x);
    o.y = f32_to_bf16(v.y);
    o.z = f32_to_bf16(v.z);
    o.w = f32_to_bf16(v.w);
    reinterpret_cast<ushort4*>(out)[i] = o;
}

// Shared inner-loop pieces (m97 structure, verified round 3):
// 128x128 tile, BK=64, 4 waves 2x2, 16x16x32 bf16 MFMA, global_load_lds w16,
// XOR swizzle: inverse-swizzled global src + swizzled ds_read, linear LDS dest.
#define BM 128
#define BN 128
#define BK 64

#define STAGE_TILES(Ablk, lda, Bblk, ldb, k0)                                        \
    _Pragma("unroll") for (int i = 0; i < 4; ++i) {                                  \
        const int c = tid + i * 256;                                                 \
        const int row = c >> 3;                                                      \
        const int jl = (c & 7) ^ (row & 7);                                          \
        const unsigned short* ga = (Ablk) + (size_t)row * (lda) + ((k0) + jl * 8);   \
        const unsigned short* gb = (Bblk) + (size_t)row * (ldb) + ((k0) + jl * 8);   \
        __builtin_amdgcn_global_load_lds(                                            \
            (const __attribute__((address_space(1))) void*)ga,                       \
            (__attribute__((address_space(3))) void*)(&As[c * 8]), 16, 0, 0);        \
        __builtin_amdgcn_global_load_lds(                                            \
            (const __attribute__((address_space(1))) void*)gb,                       \
            (__attribute__((address_space(3))) void*)(&Bs[c * 8]), 16, 0, 0);        \
    }

#define COMPUTE_TILE()                                                               \
    _Pragma("unroll") for (int ks = 0; ks < 2; ++ks) {                               \
        bf16x8 af[4], bfr[4];                                                        \
        _Pragma("unroll") for (int m = 0; m < 4; ++m) {                              \
            const int row = wr * 64 + m * 16 + (lane & 15);                          \
            const int ch = (ks * 4 + (lane >> 4)) ^ (row & 7);                       \
            af[m] = *reinterpret_cast<const bf16x8*>(                                \
                reinterpret_cast<const char*>(As) + row * 128 + ch * 16);            \
        }                                                                            \
        _Pragma("unroll") for (int n = 0; n < 4; ++n) {                              \
            const int row = wc * 64 + n * 16 + (lane & 15);                          \
            const int ch = (ks * 4 + (lane >> 4)) ^ (row & 7);                       \
            bfr[n] = *reinterpret_cast<const bf16x8*>(                               \
                reinterpret_cast<const char*>(Bs) + row * 128 + ch * 16);            \
        }                                                                            \
        _Pragma("unroll") for (int m = 0; m < 4; ++m)                                \
            _Pragma("unroll") for (int n = 0; n < 4; ++n)                            \
                acc[m][n] = __builtin_amdgcn_mfma_f32_16x16x32_bf16(                 \
                    af[m], bfr[n], acc[m][n], 0, 0, 0);                              \
    }

// ---------------- scores GEMM: S[M,N] = A[M,K] * B[N,K]^T, fp32 out ----------------
__global__ __launch_bounds__(256, 2) void gemm_nt_f32(
    const unsigned short* __restrict__ A, const unsigned short* __restrict__ B,
    float* __restrict__ C, int K, int lda, int ldb, int ldc) {
    __shared__ __align__(16) unsigned short As[BM * BK];
    __shared__ __align__(16) unsigned short Bs[BN * BK];
    const int tid = threadIdx.x;
    const int lane = tid & 63;
    const int wave = tid >> 6;
    const int wr = wave >> 1, wc = wave & 1;

    const unsigned short* Ablk = A + (size_t)blockIdx.y * BM * lda;
    const unsigned short* Bblk = B + (size_t)blockIdx.x * BN * ldb;
    f32x4 acc[4][4] = {};

    for (int k0 = 0; k0 < K; k0 += BK) {
        STAGE_TILES(Ablk, lda, Bblk, ldb, k0)
        __syncthreads();
        COMPUTE_TILE()
        __syncthreads();
    }

    const int col0 = blockIdx.x * BN + wc * 64 + (lane & 15);
    const int row0 = blockIdx.y * BM + wr * 64 + ((lane >> 4) << 2);
#pragma unroll
    for (int m = 0; m < 4; ++m)
#pragma unroll
        for (int n = 0; n < 4; ++n)
#pragma unroll
            for (int r = 0; r < 4; ++r)
                C[(size_t)(row0 + m * 16 + r) * ldc + (col0 + n * 16)] = acc[m][n][r];
}

// ---------------- fused QKV GEMM ----------------
// grid (24, 32). bx<16: QK[4096][2048] bf16 (Q cols 0-1023, K cols 1024-2047).
// bx>=16: V, written transposed into Vt[1024][4096] bf16.
__global__ __launch_bounds__(256, 2) void gemm_qkv(
    const unsigned short* __restrict__ xb, const unsigned short* __restrict__ Wb,
    unsigned short* __restrict__ QK, unsigned short* __restrict__ Vt) {
    __shared__ __align__(16) unsigned short As[BM * BK];
    __shared__ __align__(16) unsigned short Bs[BN * BK];
    const int tid = threadIdx.x;
    const int lane = tid & 63;
    const int wave = tid >> 6;
    const int wr = wave >> 1, wc = wave & 1;
    const int bx = blockIdx.x;

    const unsigned short* Ablk = xb + (size_t)blockIdx.y * BM * DMODEL;
    const unsigned short* Bblk = Wb + (size_t)bx * BN * DMODEL;
    f32x4 acc[4][4] = {};

    for (int k0 = 0; k0 < DMODEL; k0 += BK) {
        STAGE_TILES(Ablk, DMODEL, Bblk, DMODEL, k0)
        __syncthreads();
        COMPUTE_TILE()
        __syncthreads();
    }

    const int colw = wc * 64 + (lane & 15);       // col within 128-tile
    const int row0 = blockIdx.y * BM + wr * 64 + ((lane >> 4) << 2);
    if (bx < 16) {  // Q or K -> QK buffer, ldc = 2048
        const int col0 = bx * 128 + colw;
#pragma unroll
        for (int m = 0; m < 4; ++m)
#pragma unroll
            for (int n = 0; n < 4; ++n)
#pragma unroll
                for (int r = 0; r < 4; ++r)
                    QK[(size_t)(row0 + m * 16 + r) * 2048 + (col0 + n * 16)] =
                        f32_to_bf16(acc[m][n][r]);
    } else {  // V -> Vt transposed, ldc = 4096
        const int vrow0 = (bx - 16) * 128 + colw;
#pragma unroll
        for (int m = 0; m < 4; ++m)
#pragma unroll
            for (int n = 0; n < 4; ++n) {
                ushort4 o;
                o.x = f32_to_bf16(acc[m][n][0]);
                o.y = f32_to_bf16(acc[m][n][1]);
                o.z = f32_to_bf16(acc[m][n][2]);
                o.w = f32_to_bf16(acc[m][n][3]);
                *reinterpret_cast<ushort4*>(
                    &Vt[(size_t)(vrow0 + n * 16) * NTOK + (row0 + m * 16)]) = o;
            }
    }
}

// ---------------- PV GEMM, split-K=4, fp32 atomic accumulate ----------------
// grid (8, 32, 4). Each block computes a K=1024 slice of out[M,N] and atomically
// adds. Requires out zeroed first (memsetAsync in kernel_launch).
__global__ __launch_bounds__(256, 2) void gemm_pv_splitk(
    const unsigned short* __restrict__ P, const unsigned short* __restrict__ Vt,
    float* __restrict__ C) {
    __shared__ __align__(16) unsigned short As[BM * BK];
    __shared__ __align__(16) unsigned short Bs[BN * BK];
    const int tid = threadIdx.x;
    const int lane = tid & 63;
    const int wave = tid >> 6;
    const int wr = wave >> 1, wc = wave & 1;

    const unsigned short* Ablk = P + (size_t)blockIdx.y * BM * (2 * NTOK);
    const unsigned short* Bblk = Vt + (size_t)blockIdx.x * BN * NTOK;
    f32x4 acc[4][4] = {};

    const int kbeg = blockIdx.z * (NTOK / 4);
    const int kend = kbeg + NTOK / 4;
    for (int k0 = kbeg; k0 < kend; k0 += BK) {
        STAGE_TILES(Ablk, 2 * NTOK, Bblk, NTOK, k0)
        __syncthreads();
        COMPUTE_TILE()
        __syncthreads();
    }

    const int col0 = blockIdx.x * BN + wc * 64 + (lane & 15);
    const int row0 = blockIdx.y * BM + wr * 64 + ((lane >> 4) << 2);
#pragma unroll
    for (int m = 0; m < 4; ++m)
#pragma unroll
        for (int n = 0; n < 4; ++n)
#pragma unroll
            for (int r = 0; r < 4; ++r)
                unsafeAtomicAdd(&C[(size_t)(row0 + m * 16 + r) * DMODEL + (col0 + n * 16)],
                                acc[m][n][r]);
}

// ---------------- row softmax: P = softmax(S/32), bf16, in-place ----------------
__global__ __launch_bounds__(256) void softmax_rows(float* __restrict__ S, int N) {
    const int row = blockIdx.x;
    float* s = S + (size_t)row * N;
    const int t = threadIdx.x;

    float v[16];
    float mx = -1e30f;
#pragma unroll
    for (int i = 0; i < 4; ++i) {
        float4 x = reinterpret_cast<const float4*>(s)[t + i * 256];
        v[i * 4 + 0] = x.x;
        v[i * 4 + 1] = x.y;
        v[i * 4 + 2] = x.z;
        v[i * 4 + 3] = x.w;
        mx = fmaxf(mx, fmaxf(fmaxf(x.x, x.y), fmaxf(x.z, x.w)));
    }
#pragma unroll
    for (int off = 32; off; off >>= 1) mx = fmaxf(mx, __shfl_xor(mx, off));
    __shared__ float redm[4];
    if (!(t & 63)) redm[t >> 6] = mx;
    __syncthreads();
    mx = fmaxf(fmaxf(redm[0], redm[1]), fmaxf(redm[2], redm[3]));

    float sum = 0.f;
#pragma unroll
    for (int i = 0; i < 16; ++i) {
        v[i] = __expf((v[i] - mx) * 0.03125f);
        sum += v[i];
    }
#pragma unroll
    for (int off = 32; off; off >>= 1) sum += __shfl_xor(sum, off);
    __shared__ float reds[4];
    if (!(t & 63)) reds[t >> 6] = sum;
    __syncthreads();
    sum = (reds[0] + reds[1]) + (reds[2] + reds[3]);
    const float inv = 1.0f / sum;

    unsigned short* p = reinterpret_cast<unsigned short*>(s);
#pragma unroll
    for (int i = 0; i < 4; ++i) {
        ushort4 o;
        o.x = f32_to_bf16(v[i * 4 + 0] * inv);
        o.y = f32_to_bf16(v[i * 4 + 1] * inv);
        o.z = f32_to_bf16(v[i * 4 + 2] * inv);
        o.w = f32_to_bf16(v[i * 4 + 3] * inv);
        reinterpret_cast<ushort4*>(p)[t + i * 256] = o;
    }
}

extern "C" void kernel_launch(void* const* d_in, const int* in_sizes, int n_in,
                              void* d_out, int out_size, void* d_ws, size_t ws_size,
                              hipStream_t stream) {
    (void)in_sizes; (void)n_in; (void)out_size; (void)ws_size;
    const float* x = (const float*)d_in[0];
    const float* wq = (const float*)d_in[1];
    const float* wk = (const float*)d_in[2];
    const float* wv = (const float*)d_in[3];
    float* out = (float*)d_out;

    // ws layout (MiB): xb 0..8, Wb 8..14 (wq|wk|wv fused, 3072x1024 bf16),
    // QK 14..30 (4096x2048 bf16), Vt 30..38 (1024x4096 bf16),
    // S 38..102 (4096x4096 fp32; P bf16 written in-place over front half of rows)
    const size_t MB = 1ull << 20;
    char* w = (char*)d_ws;
    unsigned short* xb = (unsigned short*)(w + 0 * MB);
    unsigned short* Wb = (unsigned short*)(w + 8 * MB);
    unsigned short* QK = (unsigned short*)(w + 14 * MB);
    unsigned short* Vt = (unsigned short*)(w + 30 * MB);
    float* S           = (float*)(w + 38 * MB);

    cvt_f32_bf16<<<4096, 256, 0, stream>>>(x, xb, (NTOK * DMODEL) / 4);
    cvt_f32_bf16<<<1024, 256, 0, stream>>>(wq, Wb, (DMODEL * DMODEL) / 4);
    cvt_f32_bf16<<<1024, 256, 0, stream>>>(wk, Wb + DMODEL * DMODEL, (DMODEL * DMODEL) / 4);
    cvt_f32_bf16<<<1024, 256, 0, stream>>>(wv, Wb + 2 * DMODEL * DMODEL, (DMODEL * DMODEL) / 4);

    // fused QKV: 768 blocks (3/CU)
    gemm_qkv<<<dim3(24, 32), 256, 0, stream>>>(xb, Wb, QK, Vt);

    // scores: S = Q @ K^T, 1024 blocks (4/CU)
    gemm_nt_f32<<<dim3(32, 32), 256, 0, stream>>>(QK, QK + 1024, S, DMODEL, 2048, 2048, NTOK);

    softmax_rows<<<NTOK, 256, 0, stream>>>(S, NTOK);

    // PV: out = P @ Vt^T with split-K=4 atomic accumulate; 1024 blocks (4/CU)
    hipMemsetAsync(d_out, 0, (size_t)NTOK * DMODEL * sizeof(float), stream);
    gemm_pv_splitk<<<dim3(8, 32, 4), 256, 0, stream>>>((const unsigned short*)S, Vt, out);
}

// Round 10
// 229.137 us; speedup vs baseline: 1.1519x; 1.0971x over previous
//
#include <hip/hip_runtime.h>
#include <cstdint>

#define NTOK 4096
#define DMODEL 1024

typedef __bf16 bf16x8 __attribute__((ext_vector_type(8)));
typedef float f32x4 __attribute__((ext_vector_type(4)));

__device__ __forceinline__ unsigned short f32_to_bf16(float f) {
    unsigned int u = __float_as_uint(f);
    unsigned int r = 0x7FFFu + ((u >> 16) & 1u);
    return (unsigned short)((u + r) >> 16);
}

// ---------------- fp32 -> bf16 cast (vectorized) ----------------
__global__ __launch_bounds__(256) void cvt_f32_bf16(const float* __restrict__ in,
                                                    unsigned short* __restrict__ out,
                                                    int n4) {
    int i = blockIdx.x * 256 + threadIdx.x;
    if (i >= n4) return;
    float4 v = reinterpret_cast<const float4*>(in)[i];
    ushort4 o;
    o.x = f32_to_bf16(v.x);
    o.y = f32_to_bf16(v.y);
    o.z = f32_to_bf16(v.z);
    o.w = f32_to_bf16(v.w);
    reinterpret_cast<ushort4*>(out)[i] = o;
}

// Shared inner-loop pieces (m97 structure, verified round 3):
// 128x128 tile, BK=64, 4 waves 2x2, 16x16x32 bf16 MFMA, global_load_lds w16,
// XOR swizzle: inverse-swizzled global src + swizzled ds_read, linear LDS dest.
#define BM 128
#define BN 128
#define BK 64

#define STAGE_TILES(Ablk, lda, Bblk, ldb, k0)                                        \
    _Pragma("unroll") for (int i = 0; i < 4; ++i) {                                  \
        const int c = tid + i * 256;                                                 \
        const int row = c >> 3;                                                      \
        const int jl = (c & 7) ^ (row & 7);                                          \
        const unsigned short* ga = (Ablk) + (size_t)row * (lda) + ((k0) + jl * 8);   \
        const unsigned short* gb = (Bblk) + (size_t)row * (ldb) + ((k0) + jl * 8);   \
        __builtin_amdgcn_global_load_lds(                                            \
            (const __attribute__((address_space(1))) void*)ga,                       \
            (__attribute__((address_space(3))) void*)(&As[c * 8]), 16, 0, 0);        \
        __builtin_amdgcn_global_load_lds(                                            \
            (const __attribute__((address_space(1))) void*)gb,                       \
            (__attribute__((address_space(3))) void*)(&Bs[c * 8]), 16, 0, 0);        \
    }

#define COMPUTE_TILE()                                                               \
    _Pragma("unroll") for (int ks = 0; ks < 2; ++ks) {                               \
        bf16x8 af[4], bfr[4];                                                        \
        _Pragma("unroll") for (int m = 0; m < 4; ++m) {                              \
            const int row = wr * 64 + m * 16 + (lane & 15);                          \
            const int ch = (ks * 4 + (lane >> 4)) ^ (row & 7);                       \
            af[m] = *reinterpret_cast<const bf16x8*>(                                \
                reinterpret_cast<const char*>(As) + row * 128 + ch * 16);            \
        }                                                                            \
        _Pragma("unroll") for (int n = 0; n < 4; ++n) {                              \
            const int row = wc * 64 + n * 16 + (lane & 15);                          \
            const int ch = (ks * 4 + (lane >> 4)) ^ (row & 7);                       \
            bfr[n] = *reinterpret_cast<const bf16x8*>(                               \
                reinterpret_cast<const char*>(Bs) + row * 128 + ch * 16);            \
        }                                                                            \
        _Pragma("unroll") for (int m = 0; m < 4; ++m)                                \
            _Pragma("unroll") for (int n = 0; n < 4; ++n)                            \
                acc[m][n] = __builtin_amdgcn_mfma_f32_16x16x32_bf16(                 \
                    af[m], bfr[n], acc[m][n], 0, 0, 0);                              \
    }

// ---------------- scores GEMM: S = Q @ K^T (fp32 out) ----------------
// 1D grid 1024. XCD-chunked swizzle (bijective): g=id&7 -> XCD, s=id>>3 in [0,128);
// bx = s>>2 (K-panel, changes slowest-but-4), by = 4g + (s&3) (Q panels, 4 per XCD
// cached in L2 ~1MB while K panel is reused by 4 consecutive blocks).
__global__ __launch_bounds__(256, 2) void gemm_scores(
    const unsigned short* __restrict__ QK, float* __restrict__ S) {
    __shared__ __align__(16) unsigned short As[BM * BK];
    __shared__ __align__(16) unsigned short Bs[BN * BK];
    const int tid = threadIdx.x;
    const int lane = tid & 63;
    const int wave = tid >> 6;
    const int wr = wave >> 1, wc = wave & 1;

    const int id = blockIdx.x;
    const int g = id & 7, s = id >> 3;
    const int bx = s >> 2;
    const int by = (g << 2) + (s & 3);

    const unsigned short* Ablk = QK + (size_t)by * BM * 2048;           // Q rows
    const unsigned short* Bblk = QK + 1024 + (size_t)bx * BN * 2048;    // K rows
    f32x4 acc[4][4] = {};

    for (int k0 = 0; k0 < DMODEL; k0 += BK) {
        STAGE_TILES(Ablk, 2048, Bblk, 2048, k0)
        __syncthreads();
        COMPUTE_TILE()
        __syncthreads();
    }

    const int col0 = bx * BN + wc * 64 + (lane & 15);
    const int row0 = by * BM + wr * 64 + ((lane >> 4) << 2);
#pragma unroll
    for (int m = 0; m < 4; ++m)
#pragma unroll
        for (int n = 0; n < 4; ++n)
#pragma unroll
            for (int r = 0; r < 4; ++r)
                S[(size_t)(row0 + m * 16 + r) * NTOK + (col0 + n * 16)] = acc[m][n][r];
}

// ---------------- fused QKV GEMM ----------------
// 1D grid 768. Swizzle: g=id&7, s=id>>3 in [0,96); bx=s%24, by=4g+s/24.
// bx<16: QK[4096][2048] bf16 (Q cols 0-1023, K cols 1024-2047).
// bx>=16: V, written transposed into Vt[1024][4096] bf16.
__global__ __launch_bounds__(256, 2) void gemm_qkv(
    const unsigned short* __restrict__ xb, const unsigned short* __restrict__ Wb,
    unsigned short* __restrict__ QK, unsigned short* __restrict__ Vt) {
    __shared__ __align__(16) unsigned short As[BM * BK];
    __shared__ __align__(16) unsigned short Bs[BN * BK];
    const int tid = threadIdx.x;
    const int lane = tid & 63;
    const int wave = tid >> 6;
    const int wr = wave >> 1, wc = wave & 1;

    const int id = blockIdx.x;
    const int g = id & 7, s = id >> 3;
    const int bx = s % 24;
    const int by = (g << 2) + s / 24;

    const unsigned short* Ablk = xb + (size_t)by * BM * DMODEL;
    const unsigned short* Bblk = Wb + (size_t)bx * BN * DMODEL;
    f32x4 acc[4][4] = {};

    for (int k0 = 0; k0 < DMODEL; k0 += BK) {
        STAGE_TILES(Ablk, DMODEL, Bblk, DMODEL, k0)
        __syncthreads();
        COMPUTE_TILE()
        __syncthreads();
    }

    const int colw = wc * 64 + (lane & 15);       // col within 128-tile
    const int row0 = by * BM + wr * 64 + ((lane >> 4) << 2);
    if (bx < 16) {  // Q or K -> QK buffer, ldc = 2048
        const int col0 = bx * 128 + colw;
#pragma unroll
        for (int m = 0; m < 4; ++m)
#pragma unroll
            for (int n = 0; n < 4; ++n)
#pragma unroll
                for (int r = 0; r < 4; ++r)
                    QK[(size_t)(row0 + m * 16 + r) * 2048 + (col0 + n * 16)] =
                        f32_to_bf16(acc[m][n][r]);
    } else {  // V -> Vt transposed, ldc = 4096
        const int vrow0 = (bx - 16) * 128 + colw;
#pragma unroll
        for (int m = 0; m < 4; ++m)
#pragma unroll
            for (int n = 0; n < 4; ++n) {
                ushort4 o;
                o.x = f32_to_bf16(acc[m][n][0]);
                o.y = f32_to_bf16(acc[m][n][1]);
                o.z = f32_to_bf16(acc[m][n][2]);
                o.w = f32_to_bf16(acc[m][n][3]);
                *reinterpret_cast<ushort4*>(
                    &Vt[(size_t)(vrow0 + n * 16) * NTOK + (row0 + m * 16)]) = o;
            }
    }
}

// ---------------- PV GEMM: out = P @ Vt^T (fp32 out, full K, no atomics) --------
// 1D grid 256. Swizzle: g=id&7, s=id>>3 in [0,32); bx=s&7 (fastest: the 8 blocks
// sharing a P row-panel run consecutively on ONE XCD -> P panel L2-resident),
// by=4g+(s>>3).
__global__ __launch_bounds__(256, 2) void gemm_pv(
    const unsigned short* __restrict__ P, const unsigned short* __restrict__ Vt,
    float* __restrict__ C) {
    __shared__ __align__(16) unsigned short As[BM * BK];
    __shared__ __align__(16) unsigned short Bs[BN * BK];
    const int tid = threadIdx.x;
    const int lane = tid & 63;
    const int wave = tid >> 6;
    const int wr = wave >> 1, wc = wave & 1;

    const int id = blockIdx.x;
    const int g = id & 7, s = id >> 3;
    const int bx = s & 7;
    const int by = (g << 2) + (s >> 3);

    const unsigned short* Ablk = P + (size_t)by * BM * (2 * NTOK);
    const unsigned short* Bblk = Vt + (size_t)bx * BN * NTOK;
    f32x4 acc[4][4] = {};

    for (int k0 = 0; k0 < NTOK; k0 += BK) {
        STAGE_TILES(Ablk, 2 * NTOK, Bblk, NTOK, k0)
        __syncthreads();
        COMPUTE_TILE()
        __syncthreads();
    }

    const int col0 = bx * BN + wc * 64 + (lane & 15);
    const int row0 = by * BM + wr * 64 + ((lane >> 4) << 2);
#pragma unroll
    for (int m = 0; m < 4; ++m)
#pragma unroll
        for (int n = 0; n < 4; ++n)
#pragma unroll
            for (int r = 0; r < 4; ++r)
                C[(size_t)(row0 + m * 16 + r) * DMODEL + (col0 + n * 16)] = acc[m][n][r];
}

// ---------------- row softmax: P = softmax(S/32), bf16, in-place ----------------
__global__ __launch_bounds__(256) void softmax_rows(float* __restrict__ S, int N) {
    const int row = blockIdx.x;
    float* s = S + (size_t)row * N;
    const int t = threadIdx.x;

    float v[16];
    float mx = -1e30f;
#pragma unroll
    for (int i = 0; i < 4; ++i) {
        float4 x = reinterpret_cast<const float4*>(s)[t + i * 256];
        v[i * 4 + 0] = x.x;
        v[i * 4 + 1] = x.y;
        v[i * 4 + 2] = x.z;
        v[i * 4 + 3] = x.w;
        mx = fmaxf(mx, fmaxf(fmaxf(x.x, x.y), fmaxf(x.z, x.w)));
    }
#pragma unroll
    for (int off = 32; off; off >>= 1) mx = fmaxf(mx, __shfl_xor(mx, off));
    __shared__ float redm[4];
    if (!(t & 63)) redm[t >> 6] = mx;
    __syncthreads();
    mx = fmaxf(fmaxf(redm[0], redm[1]), fmaxf(redm[2], redm[3]));

    float sum = 0.f;
#pragma unroll
    for (int i = 0; i < 16; ++i) {
        v[i] = __expf((v[i] - mx) * 0.03125f);
        sum += v[i];
    }
#pragma unroll
    for (int off = 32; off; off >>= 1) sum += __shfl_xor(sum, off);
    __shared__ float reds[4];
    if (!(t & 63)) reds[t >> 6] = sum;
    __syncthreads();
    sum = (reds[0] + reds[1]) + (reds[2] + reds[3]);
    const float inv = 1.0f / sum;

    unsigned short* p = reinterpret_cast<unsigned short*>(s);
#pragma unroll
    for (int i = 0; i < 4; ++i) {
        ushort4 o;
        o.x = f32_to_bf16(v[i * 4 + 0] * inv);
        o.y = f32_to_bf16(v[i * 4 + 1] * inv);
        o.z = f32_to_bf16(v[i * 4 + 2] * inv);
        o.w = f32_to_bf16(v[i * 4 + 3] * inv);
        reinterpret_cast<ushort4*>(p)[t + i * 256] = o;
    }
}

extern "C" void kernel_launch(void* const* d_in, const int* in_sizes, int n_in,
                              void* d_out, int out_size, void* d_ws, size_t ws_size,
                              hipStream_t stream) {
    (void)in_sizes; (void)n_in; (void)out_size; (void)ws_size;
    const float* x = (const float*)d_in[0];
    const float* wq = (const float*)d_in[1];
    const float* wk = (const float*)d_in[2];
    const float* wv = (const float*)d_in[3];
    float* out = (float*)d_out;

    // ws layout (MiB): xb 0..8, Wb 8..14 (wq|wk|wv fused, 3072x1024 bf16),
    // QK 14..30 (4096x2048 bf16), Vt 30..38 (1024x4096 bf16),
    // S 38..102 (4096x4096 fp32; P bf16 written in-place over front half of rows)
    const size_t MB = 1ull << 20;
    char* w = (char*)d_ws;
    unsigned short* xb = (unsigned short*)(w + 0 * MB);
    unsigned short* Wb = (unsigned short*)(w + 8 * MB);
    unsigned short* QK = (unsigned short*)(w + 14 * MB);
    unsigned short* Vt = (unsigned short*)(w + 30 * MB);
    float* S           = (float*)(w + 38 * MB);

    cvt_f32_bf16<<<4096, 256, 0, stream>>>(x, xb, (NTOK * DMODEL) / 4);
    cvt_f32_bf16<<<1024, 256, 0, stream>>>(wq, Wb, (DMODEL * DMODEL) / 4);
    cvt_f32_bf16<<<1024, 256, 0, stream>>>(wk, Wb + DMODEL * DMODEL, (DMODEL * DMODEL) / 4);
    cvt_f32_bf16<<<1024, 256, 0, stream>>>(wv, Wb + 2 * DMODEL * DMODEL, (DMODEL * DMODEL) / 4);

    // fused QKV: 768 blocks, XCD-swizzled
    gemm_qkv<<<768, 256, 0, stream>>>(xb, Wb, QK, Vt);

    // scores: S = Q @ K^T, 1024 blocks, XCD-swizzled
    gemm_scores<<<1024, 256, 0, stream>>>(QK, S);

    softmax_rows<<<NTOK, 256, 0, stream>>>(S, NTOK);

    // PV: out = P @ Vt^T, 256 blocks, XCD-swizzled, plain stores
    gemm_pv<<<256, 256, 0, stream>>>((const unsigned short*)S, Vt, out);
}

// Round 11
// 225.445 us; speedup vs baseline: 1.1708x; 1.0164x over previous
//
#include <hip/hip_runtime.h>
#include <cstdint>

#define NTOK 4096
#define DMODEL 1024

typedef __bf16 bf16x8 __attribute__((ext_vector_type(8)));
typedef float f32x4 __attribute__((ext_vector_type(4)));

__device__ __forceinline__ unsigned short f32_to_bf16(float f) {
    unsigned int u = __float_as_uint(f);
    unsigned int r = 0x7FFFu + ((u >> 16) & 1u);
    return (unsigned short)((u + r) >> 16);
}

// ---------------- fp32 -> bf16 cast (vectorized) ----------------
__global__ __launch_bounds__(256) void cvt_f32_bf16(const float* __restrict__ in,
                                                    unsigned short* __restrict__ out,
                                                    int n4) {
    int i = blockIdx.x * 256 + threadIdx.x;
    if (i >= n4) return;
    float4 v = reinterpret_cast<const float4*>(in)[i];
    ushort4 o;
    o.x = f32_to_bf16(v.x);
    o.y = f32_to_bf16(v.y);
    o.z = f32_to_bf16(v.z);
    o.w = f32_to_bf16(v.w);
    reinterpret_cast<ushort4*>(out)[i] = o;
}

// Shared inner-loop pieces (m97 structure, verified round 3):
// 128x128 tile, BK=64, 4 waves 2x2, 16x16x32 bf16 MFMA, global_load_lds w16,
// XOR swizzle: inverse-swizzled global src + swizzled ds_read, linear LDS dest.
#define BM 128
#define BN 128
#define BK 64

#define STAGE_TILES(Ablk, lda, Bblk, ldb, k0)                                        \
    _Pragma("unroll") for (int i = 0; i < 4; ++i) {                                  \
        const int c = tid + i * 256;                                                 \
        const int row = c >> 3;                                                      \
        const int jl = (c & 7) ^ (row & 7);                                          \
        const unsigned short* ga = (Ablk) + (size_t)row * (lda) + ((k0) + jl * 8);   \
        const unsigned short* gb = (Bblk) + (size_t)row * (ldb) + ((k0) + jl * 8);   \
        __builtin_amdgcn_global_load_lds(                                            \
            (const __attribute__((address_space(1))) void*)ga,                       \
            (__attribute__((address_space(3))) void*)(&As[c * 8]), 16, 0, 0);        \
        __builtin_amdgcn_global_load_lds(                                            \
            (const __attribute__((address_space(1))) void*)gb,                       \
            (__attribute__((address_space(3))) void*)(&Bs[c * 8]), 16, 0, 0);        \
    }

#define COMPUTE_TILE()                                                               \
    _Pragma("unroll") for (int ks = 0; ks < 2; ++ks) {                               \
        bf16x8 af[4], bfr[4];                                                        \
        _Pragma("unroll") for (int m = 0; m < 4; ++m) {                              \
            const int row = wr * 64 + m * 16 + (lane & 15);                          \
            const int ch = (ks * 4 + (lane >> 4)) ^ (row & 7);                       \
            af[m] = *reinterpret_cast<const bf16x8*>(                                \
                reinterpret_cast<const char*>(As) + row * 128 + ch * 16);            \
        }                                                                            \
        _Pragma("unroll") for (int n = 0; n < 4; ++n) {                              \
            const int row = wc * 64 + n * 16 + (lane & 15);                          \
            const int ch = (ks * 4 + (lane >> 4)) ^ (row & 7);                       \
            bfr[n] = *reinterpret_cast<const bf16x8*>(                               \
                reinterpret_cast<const char*>(Bs) + row * 128 + ch * 16);            \
        }                                                                            \
        _Pragma("unroll") for (int m = 0; m < 4; ++m)                                \
            _Pragma("unroll") for (int n = 0; n < 4; ++n)                            \
                acc[m][n] = __builtin_amdgcn_mfma_f32_16x16x32_bf16(                 \
                    af[m], bfr[n], acc[m][n], 0, 0, 0);                              \
    }

// ---------------- scores GEMM: S = Q @ K^T (fp32 out) ----------------
// 1D grid 1024. XCD-chunked swizzle (bijective): g=id&7 -> XCD, s=id>>3 in [0,128);
// bx = s>>2 (K-panel), by = 4g + (s&3) (Q panels, 4 per XCD L2-cached).
__global__ __launch_bounds__(256, 2) void gemm_scores(
    const unsigned short* __restrict__ QK, float* __restrict__ S) {
    __shared__ __align__(16) unsigned short As[BM * BK];
    __shared__ __align__(16) unsigned short Bs[BN * BK];
    const int tid = threadIdx.x;
    const int lane = tid & 63;
    const int wave = tid >> 6;
    const int wr = wave >> 1, wc = wave & 1;

    const int id = blockIdx.x;
    const int g = id & 7, s = id >> 3;
    const int bx = s >> 2;
    const int by = (g << 2) + (s & 3);

    const unsigned short* Ablk = QK + (size_t)by * BM * 2048;           // Q rows
    const unsigned short* Bblk = QK + 1024 + (size_t)bx * BN * 2048;    // K rows
    f32x4 acc[4][4] = {};

    for (int k0 = 0; k0 < DMODEL; k0 += BK) {
        STAGE_TILES(Ablk, 2048, Bblk, 2048, k0)
        __syncthreads();
        COMPUTE_TILE()
        __syncthreads();
    }

    const int col0 = bx * BN + wc * 64 + (lane & 15);
    const int row0 = by * BM + wr * 64 + ((lane >> 4) << 2);
#pragma unroll
    for (int m = 0; m < 4; ++m)
#pragma unroll
        for (int n = 0; n < 4; ++n)
#pragma unroll
            for (int r = 0; r < 4; ++r)
                S[(size_t)(row0 + m * 16 + r) * NTOK + (col0 + n * 16)] = acc[m][n][r];
}

// ---------------- fused QKV GEMM ----------------
// 1D grid 768. Swizzle: g=id&7, s=id>>3 in [0,96); bx=s%24, by=4g+s/24.
// bx<16: QK[4096][2048] bf16 (Q cols 0-1023, K cols 1024-2047).
// bx>=16: V, written transposed into Vt[1024][4096] bf16.
__global__ __launch_bounds__(256, 2) void gemm_qkv(
    const unsigned short* __restrict__ xb, const unsigned short* __restrict__ Wb,
    unsigned short* __restrict__ QK, unsigned short* __restrict__ Vt) {
    __shared__ __align__(16) unsigned short As[BM * BK];
    __shared__ __align__(16) unsigned short Bs[BN * BK];
    const int tid = threadIdx.x;
    const int lane = tid & 63;
    const int wave = tid >> 6;
    const int wr = wave >> 1, wc = wave & 1;

    const int id = blockIdx.x;
    const int g = id & 7, s = id >> 3;
    const int bx = s % 24;
    const int by = (g << 2) + s / 24;

    const unsigned short* Ablk = xb + (size_t)by * BM * DMODEL;
    const unsigned short* Bblk = Wb + (size_t)bx * BN * DMODEL;
    f32x4 acc[4][4] = {};

    for (int k0 = 0; k0 < DMODEL; k0 += BK) {
        STAGE_TILES(Ablk, DMODEL, Bblk, DMODEL, k0)
        __syncthreads();
        COMPUTE_TILE()
        __syncthreads();
    }

    const int colw = wc * 64 + (lane & 15);       // col within 128-tile
    const int row0 = by * BM + wr * 64 + ((lane >> 4) << 2);
    if (bx < 16) {  // Q or K -> QK buffer, ldc = 2048
        const int col0 = bx * 128 + colw;
#pragma unroll
        for (int m = 0; m < 4; ++m)
#pragma unroll
            for (int n = 0; n < 4; ++n)
#pragma unroll
                for (int r = 0; r < 4; ++r)
                    QK[(size_t)(row0 + m * 16 + r) * 2048 + (col0 + n * 16)] =
                        f32_to_bf16(acc[m][n][r]);
    } else {  // V -> Vt transposed, ldc = 4096
        const int vrow0 = (bx - 16) * 128 + colw;
#pragma unroll
        for (int m = 0; m < 4; ++m)
#pragma unroll
            for (int n = 0; n < 4; ++n) {
                ushort4 o;
                o.x = f32_to_bf16(acc[m][n][0]);
                o.y = f32_to_bf16(acc[m][n][1]);
                o.z = f32_to_bf16(acc[m][n][2]);
                o.w = f32_to_bf16(acc[m][n][3]);
                *reinterpret_cast<ushort4*>(
                    &Vt[(size_t)(vrow0 + n * 16) * NTOK + (row0 + m * 16)]) = o;
            }
    }
}

// ---------------- PV GEMM: out = P @ Vt^T, 128x64 tile, 2 blocks/CU ----------------
// 1D grid 512. Round-10 PMC: 1 block/CU left the 2-barrier loop latency-bound
// (MfmaUtil 19.6%, HBM 1 TB/s). 128x64 tile -> 512 blocks = 2/CU so phase-shifted
// blocks overlap each other's vmcnt drain. Swizzle (bijective): g=id&7,
// s=id>>3 in [0,64); bx=s&15 (16 bx-siblings sharing a 1MB P panel on one XCD),
// by=4g+(s>>4). LDS 24KB. acc 4x2. Accumulation order per element unchanged.
__global__ __launch_bounds__(256, 2) void gemm_pv(
    const unsigned short* __restrict__ P, const unsigned short* __restrict__ Vt,
    float* __restrict__ C) {
    __shared__ __align__(16) unsigned short As[128 * BK];
    __shared__ __align__(16) unsigned short Bs[64 * BK];
    const int tid = threadIdx.x;
    const int lane = tid & 63;
    const int wave = tid >> 6;
    const int wr = wave >> 1, wc = wave & 1;

    const int id = blockIdx.x;
    const int g = id & 7, s = id >> 3;
    const int bx = s & 15;
    const int by = (g << 2) + (s >> 4);

    const unsigned short* Ablk = P + (size_t)by * 128 * (2 * NTOK);
    const unsigned short* Bblk = Vt + (size_t)bx * 64 * NTOK;
    f32x4 acc[4][2] = {};

    for (int k0 = 0; k0 < NTOK; k0 += BK) {
        // stage A: 128x64 bf16 (1024 x 16B chunks), B: 64x64 (512 chunks)
#pragma unroll
        for (int i = 0; i < 4; ++i) {
            const int c = tid + i * 256;
            const int row = c >> 3;
            const int jl = (c & 7) ^ (row & 7);
            const unsigned short* ga = Ablk + (size_t)row * (2 * NTOK) + (k0 + jl * 8);
            __builtin_amdgcn_global_load_lds(
                (const __attribute__((address_space(1))) void*)ga,
                (__attribute__((address_space(3))) void*)(&As[c * 8]), 16, 0, 0);
        }
#pragma unroll
        for (int i = 0; i < 2; ++i) {
            const int c = tid + i * 256;
            const int row = c >> 3;
            const int jl = (c & 7) ^ (row & 7);
            const unsigned short* gb = Bblk + (size_t)row * NTOK + (k0 + jl * 8);
            __builtin_amdgcn_global_load_lds(
                (const __attribute__((address_space(1))) void*)gb,
                (__attribute__((address_space(3))) void*)(&Bs[c * 8]), 16, 0, 0);
        }
        __syncthreads();

#pragma unroll
        for (int ks = 0; ks < 2; ++ks) {
            bf16x8 af[4], bfr[2];
#pragma unroll
            for (int m = 0; m < 4; ++m) {
                const int row = wr * 64 + m * 16 + (lane & 15);
                const int ch = (ks * 4 + (lane >> 4)) ^ (row & 7);
                af[m] = *reinterpret_cast<const bf16x8*>(
                    reinterpret_cast<const char*>(As) + row * 128 + ch * 16);
            }
#pragma unroll
            for (int n = 0; n < 2; ++n) {
                const int row = wc * 32 + n * 16 + (lane & 15);
                const int ch = (ks * 4 + (lane >> 4)) ^ (row & 7);
                bfr[n] = *reinterpret_cast<const bf16x8*>(
                    reinterpret_cast<const char*>(Bs) + row * 128 + ch * 16);
            }
#pragma unroll
            for (int m = 0; m < 4; ++m)
#pragma unroll
                for (int n = 0; n < 2; ++n)
                    acc[m][n] = __builtin_amdgcn_mfma_f32_16x16x32_bf16(
                        af[m], bfr[n], acc[m][n], 0, 0, 0);
        }
        __syncthreads();
    }

    const int col0 = bx * 64 + wc * 32 + (lane & 15);
    const int row0 = by * 128 + wr * 64 + ((lane >> 4) << 2);
#pragma unroll
    for (int m = 0; m < 4; ++m)
#pragma unroll
        for (int n = 0; n < 2; ++n)
#pragma unroll
            for (int r = 0; r < 4; ++r)
                C[(size_t)(row0 + m * 16 + r) * DMODEL + (col0 + n * 16)] = acc[m][n][r];
}

// ---------------- row softmax: P = softmax(S/32), bf16, in-place ----------------
__global__ __launch_bounds__(256) void softmax_rows(float* __restrict__ S, int N) {
    const int row = blockIdx.x;
    float* s = S + (size_t)row * N;
    const int t = threadIdx.x;

    float v[16];
    float mx = -1e30f;
#pragma unroll
    for (int i = 0; i < 4; ++i) {
        float4 x = reinterpret_cast<const float4*>(s)[t + i * 256];
        v[i * 4 + 0] = x.x;
        v[i * 4 + 1] = x.y;
        v[i * 4 + 2] = x.z;
        v[i * 4 + 3] = x.w;
        mx = fmaxf(mx, fmaxf(fmaxf(x.x, x.y), fmaxf(x.z, x.w)));
    }
#pragma unroll
    for (int off = 32; off; off >>= 1) mx = fmaxf(mx, __shfl_xor(mx, off));
    __shared__ float redm[4];
    if (!(t & 63)) redm[t >> 6] = mx;
    __syncthreads();
    mx = fmaxf(fmaxf(redm[0], redm[1]), fmaxf(redm[2], redm[3]));

    float sum = 0.f;
#pragma unroll
    for (int i = 0; i < 16; ++i) {
        v[i] = __expf((v[i] - mx) * 0.03125f);
        sum += v[i];
    }
#pragma unroll
    for (int off = 32; off; off >>= 1) sum += __shfl_xor(sum, off);
    __shared__ float reds[4];
    if (!(t & 63)) reds[t >> 6] = sum;
    __syncthreads();
    sum = (reds[0] + reds[1]) + (reds[2] + reds[3]);
    const float inv = 1.0f / sum;

    unsigned short* p = reinterpret_cast<unsigned short*>(s);
#pragma unroll
    for (int i = 0; i < 4; ++i) {
        ushort4 o;
        o.x = f32_to_bf16(v[i * 4 + 0] * inv);
        o.y = f32_to_bf16(v[i * 4 + 1] * inv);
        o.z = f32_to_bf16(v[i * 4 + 2] * inv);
        o.w = f32_to_bf16(v[i * 4 + 3] * inv);
        reinterpret_cast<ushort4*>(p)[t + i * 256] = o;
    }
}

extern "C" void kernel_launch(void* const* d_in, const int* in_sizes, int n_in,
                              void* d_out, int out_size, void* d_ws, size_t ws_size,
                              hipStream_t stream) {
    (void)in_sizes; (void)n_in; (void)out_size; (void)ws_size;
    const float* x = (const float*)d_in[0];
    const float* wq = (const float*)d_in[1];
    const float* wk = (const float*)d_in[2];
    const float* wv = (const float*)d_in[3];
    float* out = (float*)d_out;

    // ws layout (MiB): xb 0..8, Wb 8..14 (wq|wk|wv fused, 3072x1024 bf16),
    // QK 14..30 (4096x2048 bf16), Vt 30..38 (1024x4096 bf16),
    // S 38..102 (4096x4096 fp32; P bf16 written in-place over front half of rows)
    const size_t MB = 1ull << 20;
    char* w = (char*)d_ws;
    unsigned short* xb = (unsigned short*)(w + 0 * MB);
    unsigned short* Wb = (unsigned short*)(w + 8 * MB);
    unsigned short* QK = (unsigned short*)(w + 14 * MB);
    unsigned short* Vt = (unsigned short*)(w + 30 * MB);
    float* S           = (float*)(w + 38 * MB);

    cvt_f32_bf16<<<4096, 256, 0, stream>>>(x, xb, (NTOK * DMODEL) / 4);
    cvt_f32_bf16<<<1024, 256, 0, stream>>>(wq, Wb, (DMODEL * DMODEL) / 4);
    cvt_f32_bf16<<<1024, 256, 0, stream>>>(wk, Wb + DMODEL * DMODEL, (DMODEL * DMODEL) / 4);
    cvt_f32_bf16<<<1024, 256, 0, stream>>>(wv, Wb + 2 * DMODEL * DMODEL, (DMODEL * DMODEL) / 4);

    // fused QKV: 768 blocks, XCD-swizzled
    gemm_qkv<<<768, 256, 0, stream>>>(xb, Wb, QK, Vt);

    // scores: S = Q @ K^T, 1024 blocks, XCD-swizzled
    gemm_scores<<<1024, 256, 0, stream>>>(QK, S);

    softmax_rows<<<NTOK, 256, 0, stream>>>(S, NTOK);

    // PV: out = P @ Vt^T, 512 blocks (2/CU), 128x64 tile, XCD-swizzled
    gemm_pv<<<512, 256, 0, stream>>>((const unsigned short*)S, Vt, out);
}

// Round 15
// 220.725 us; speedup vs baseline: 1.1959x; 1.0214x over previous
//
#include <hip/hip_runtime.h>
#include <cstdint>

#define NTOK 4096
#define DMODEL 1024

typedef __bf16 bf16x8 __attribute__((ext_vector_type(8)));
typedef float f32x4 __attribute__((ext_vector_type(4)));

__device__ __forceinline__ unsigned short f32_to_bf16(float f) {
    unsigned int u = __float_as_uint(f);
    unsigned int r = 0x7FFFu + ((u >> 16) & 1u);
    return (unsigned short)((u + r) >> 16);
}

// ---------------- fp32 -> bf16 cast (vectorized) ----------------
__global__ __launch_bounds__(256) void cvt_f32_bf16(const float* __restrict__ in,
                                                    unsigned short* __restrict__ out,
                                                    int n4) {
    int i = blockIdx.x * 256 + threadIdx.x;
    if (i >= n4) return;
    float4 v = reinterpret_cast<const float4*>(in)[i];
    ushort4 o;
    o.x = f32_to_bf16(v.x);
    o.y = f32_to_bf16(v.y);
    o.z = f32_to_bf16(v.z);
    o.w = f32_to_bf16(v.w);
    reinterpret_cast<ushort4*>(out)[i] = o;
}

// m97 inner pieces + 2-phase double-buffer (round 12): stage t+1 into buf^1
// BEFORE computing t; ONE barrier/iter (its implicit vmcnt/lgkm drain lands the
// loads that overlapped compute). Even-NT 2-step unroll -> static buffer refs.
#define BM 128
#define BN 128
#define BK 64

#define STAGE_DB(As_, Bs_, Ablk, lda, Bblk, ldb, k0)                                 \
    _Pragma("unroll") for (int i = 0; i < 4; ++i) {                                  \
        const int c = tid + i * 256;                                                 \
        const int row = c >> 3;                                                      \
        const int jl = (c & 7) ^ (row & 7);                                          \
        const unsigned short* ga = (Ablk) + (size_t)row * (lda) + ((k0) + jl * 8);   \
        const unsigned short* gb = (Bblk) + (size_t)row * (ldb) + ((k0) + jl * 8);   \
        __builtin_amdgcn_global_load_lds(                                            \
            (const __attribute__((address_space(1))) void*)ga,                       \
            (__attribute__((address_space(3))) void*)(&(As_)[c * 8]), 16, 0, 0);     \
        __builtin_amdgcn_global_load_lds(                                            \
            (const __attribute__((address_space(1))) void*)gb,                       \
            (__attribute__((address_space(3))) void*)(&(Bs_)[c * 8]), 16, 0, 0);     \
    }

#define COMPUTE_DB(As_, Bs_)                                                         \
    _Pragma("unroll") for (int ks = 0; ks < 2; ++ks) {                               \
        bf16x8 af[4], bfr[4];                                                        \
        _Pragma("unroll") for (int m = 0; m < 4; ++m) {                              \
            const int row = wr * 64 + m * 16 + (lane & 15);                          \
            const int ch = (ks * 4 + (lane >> 4)) ^ (row & 7);                       \
            af[m] = *reinterpret_cast<const bf16x8*>(                                \
                reinterpret_cast<const char*>(As_) + row * 128 + ch * 16);           \
        }                                                                            \
        _Pragma("unroll") for (int n = 0; n < 4; ++n) {                              \
            const int row = wc * 64 + n * 16 + (lane & 15);                          \
            const int ch = (ks * 4 + (lane >> 4)) ^ (row & 7);                       \
            bfr[n] = *reinterpret_cast<const bf16x8*>(                               \
                reinterpret_cast<const char*>(Bs_) + row * 128 + ch * 16);           \
        }                                                                            \
        _Pragma("unroll") for (int m = 0; m < 4; ++m)                                \
            _Pragma("unroll") for (int n = 0; n < 4; ++n)                            \
                acc[m][n] = __builtin_amdgcn_mfma_f32_16x16x32_bf16(                 \
                    af[m], bfr[n], acc[m][n], 0, 0, 0);                              \
    }

// ---------------- scores GEMM: S = Q @ K^T (fp32 out), 2-phase dbuf ----------------
// 1D grid 1024, XCD-chunked swizzle (bijective), NT = 16 K-steps.
__global__ __launch_bounds__(256, 2) void gemm_scores(
    const unsigned short* __restrict__ QK, float* __restrict__ S) {
    __shared__ __align__(16) unsigned short As0[BM * BK], Bs0[BN * BK];
    __shared__ __align__(16) unsigned short As1[BM * BK], Bs1[BN * BK];
    const int tid = threadIdx.x;
    const int lane = tid & 63;
    const int wave = tid >> 6;
    const int wr = wave >> 1, wc = wave & 1;

    const int id = blockIdx.x;
    const int g = id & 7, s = id >> 3;
    const int bx = s >> 2;
    const int by = (g << 2) + (s & 3);

    const unsigned short* Ablk = QK + (size_t)by * BM * 2048;           // Q rows
    const unsigned short* Bblk = QK + 1024 + (size_t)bx * BN * 2048;    // K rows
    f32x4 acc[4][4] = {};

    STAGE_DB(As0, Bs0, Ablk, 2048, Bblk, 2048, 0)
    __syncthreads();
#pragma unroll 1
    for (int t = 0; t < 16; t += 2) {
        STAGE_DB(As1, Bs1, Ablk, 2048, Bblk, 2048, (t + 1) * BK)
        COMPUTE_DB(As0, Bs0)
        __syncthreads();
        if (t + 2 < 16) STAGE_DB(As0, Bs0, Ablk, 2048, Bblk, 2048, (t + 2) * BK)
        COMPUTE_DB(As1, Bs1)
        __syncthreads();
    }

    const int col0 = bx * BN + wc * 64 + (lane & 15);
    const int row0 = by * BM + wr * 64 + ((lane >> 4) << 2);
#pragma unroll
    for (int m = 0; m < 4; ++m)
#pragma unroll
        for (int n = 0; n < 4; ++n)
#pragma unroll
            for (int r = 0; r < 4; ++r)
                S[(size_t)(row0 + m * 16 + r) * NTOK + (col0 + n * 16)] = acc[m][n][r];
}

// ---------------- fused QKV GEMM, 2-phase dbuf ----------------
// 1D grid 768. Swizzle: g=id&7, s=id>>3 in [0,96); bx=s%24, by=4g+s/24. NT=16.
__global__ __launch_bounds__(256, 2) void gemm_qkv(
    const unsigned short* __restrict__ xb, const unsigned short* __restrict__ Wb,
    unsigned short* __restrict__ QK, unsigned short* __restrict__ Vt) {
    __shared__ __align__(16) unsigned short As0[BM * BK], Bs0[BN * BK];
    __shared__ __align__(16) unsigned short As1[BM * BK], Bs1[BN * BK];
    const int tid = threadIdx.x;
    const int lane = tid & 63;
    const int wave = tid >> 6;
    const int wr = wave >> 1, wc = wave & 1;

    const int id = blockIdx.x;
    const int g = id & 7, s = id >> 3;
    const int bx = s % 24;
    const int by = (g << 2) + s / 24;

    const unsigned short* Ablk = xb + (size_t)by * BM * DMODEL;
    const unsigned short* Bblk = Wb + (size_t)bx * BN * DMODEL;
    f32x4 acc[4][4] = {};

    STAGE_DB(As0, Bs0, Ablk, DMODEL, Bblk, DMODEL, 0)
    __syncthreads();
#pragma unroll 1
    for (int t = 0; t < 16; t += 2) {
        STAGE_DB(As1, Bs1, Ablk, DMODEL, Bblk, DMODEL, (t + 1) * BK)
        COMPUTE_DB(As0, Bs0)
        __syncthreads();
        if (t + 2 < 16) STAGE_DB(As0, Bs0, Ablk, DMODEL, Bblk, DMODEL, (t + 2) * BK)
        COMPUTE_DB(As1, Bs1)
        __syncthreads();
    }

    const int colw = wc * 64 + (lane & 15);       // col within 128-tile
    const int row0 = by * BM + wr * 64 + ((lane >> 4) << 2);
    if (bx < 16) {  // Q or K -> QK buffer, ldc = 2048
        const int col0 = bx * 128 + colw;
#pragma unroll
        for (int m = 0; m < 4; ++m)
#pragma unroll
            for (int n = 0; n < 4; ++n)
#pragma unroll
                for (int r = 0; r < 4; ++r)
                    QK[(size_t)(row0 + m * 16 + r) * 2048 + (col0 + n * 16)] =
                        f32_to_bf16(acc[m][n][r]);
    } else {  // V -> Vt transposed, ldc = 4096
        const int vrow0 = (bx - 16) * 128 + colw;
#pragma unroll
        for (int m = 0; m < 4; ++m)
#pragma unroll
            for (int n = 0; n < 4; ++n) {
                ushort4 o;
                o.x = f32_to_bf16(acc[m][n][0]);
                o.y = f32_to_bf16(acc[m][n][1]);
                o.z = f32_to_bf16(acc[m][n][2]);
                o.w = f32_to_bf16(acc[m][n][3]);
                *reinterpret_cast<ushort4*>(
                    &Vt[(size_t)(vrow0 + n * 16) * NTOK + (row0 + m * 16)]) = o;
            }
    }
}

// ---------------- PV GEMM: out = P @ Vt^T, 128x64 tile, 2-phase dbuf ----------------
// 1D grid 512 (2 blocks/CU). Swizzle: g=id&7, s=id>>3; bx=s&15, by=4g+(s>>4). NT=64.
#define PV_STAGE(As_, Bs_, k0)                                                        \
    _Pragma("unroll") for (int i = 0; i < 4; ++i) {                                   \
        const int c = tid + i * 256;                                                  \
        const int row = c >> 3;                                                       \
        const int jl = (c & 7) ^ (row & 7);                                           \
        const unsigned short* ga = Ablk + (size_t)row * (2 * NTOK) + ((k0) + jl * 8); \
        __builtin_amdgcn_global_load_lds(                                             \
            (const __attribute__((address_space(1))) void*)ga,                        \
            (__attribute__((address_space(3))) void*)(&(As_)[c * 8]), 16, 0, 0);      \
    }                                                                                 \
    _Pragma("unroll") for (int i = 0; i < 2; ++i) {                                   \
        const int c = tid + i * 256;                                                  \
        const int row = c >> 3;                                                       \
        const int jl = (c & 7) ^ (row & 7);                                           \
        const unsigned short* gb = Bblk + (size_t)row * NTOK + ((k0) + jl * 8);       \
        __builtin_amdgcn_global_load_lds(                                             \
            (const __attribute__((address_space(1))) void*)gb,                        \
            (__attribute__((address_space(3))) void*)(&(Bs_)[c * 8]), 16, 0, 0);      \
    }

#define PV_COMPUTE(As_, Bs_)                                                          \
    _Pragma("unroll") for (int ks = 0; ks < 2; ++ks) {                                \
        bf16x8 af[4], bfr[2];                                                         \
        _Pragma("unroll") for (int m = 0; m < 4; ++m) {                               \
            const int row = wr * 64 + m * 16 + (lane & 15);                           \
            const int ch = (ks * 4 + (lane >> 4)) ^ (row & 7);                        \
            af[m] = *reinterpret_cast<const bf16x8*>(                                 \
                reinterpret_cast<const char*>(As_) + row * 128 + ch * 16);            \
        }                                                                             \
        _Pragma("unroll") for (int n = 0; n < 2; ++n) {                               \
            const int row = wc * 32 + n * 16 + (lane & 15);                           \
            const int ch = (ks * 4 + (lane >> 4)) ^ (row & 7);                        \
            bfr[n] = *reinterpret_cast<const bf16x8*>(                                \
                reinterpret_cast<const char*>(Bs_) + row * 128 + ch * 16);            \
        }                                                                             \
        _Pragma("unroll") for (int m = 0; m < 4; ++m)                                 \
            _Pragma("unroll") for (int n = 0; n < 2; ++n)                             \
                acc[m][n] = __builtin_amdgcn_mfma_f32_16x16x32_bf16(                  \
                    af[m], bfr[n], acc[m][n], 0, 0, 0);                               \
    }

__global__ __launch_bounds__(256, 2) void gemm_pv(
    const unsigned short* __restrict__ P, const unsigned short* __restrict__ Vt,
    float* __restrict__ C) {
    __shared__ __align__(16) unsigned short As0[128 * BK], Bs0[64 * BK];
    __shared__ __align__(16) unsigned short As1[128 * BK], Bs1[64 * BK];
    const int tid = threadIdx.x;
    const int lane = tid & 63;
    const int wave = tid >> 6;
    const int wr = wave >> 1, wc = wave & 1;

    const int id = blockIdx.x;
    const int g = id & 7, s = id >> 3;
    const int bx = s & 15;
    const int by = (g << 2) + (s >> 4);

    const unsigned short* Ablk = P + (size_t)by * 128 * (2 * NTOK);
    const unsigned short* Bblk = Vt + (size_t)bx * 64 * NTOK;
    f32x4 acc[4][2] = {};

    PV_STAGE(As0, Bs0, 0)
    __syncthreads();
#pragma unroll 1
    for (int t = 0; t < 64; t += 2) {
        PV_STAGE(As1, Bs1, (t + 1) * BK)
        PV_COMPUTE(As0, Bs0)
        __syncthreads();
        if (t + 2 < 64) PV_STAGE(As0, Bs0, (t + 2) * BK)
        PV_COMPUTE(As1, Bs1)
        __syncthreads();
    }

    const int col0 = bx * 64 + wc * 32 + (lane & 15);
    const int row0 = by * 128 + wr * 64 + ((lane >> 4) << 2);
#pragma unroll
    for (int m = 0; m < 4; ++m)
#pragma unroll
        for (int n = 0; n < 2; ++n)
#pragma unroll
            for (int r = 0; r < 4; ++r)
                C[(size_t)(row0 + m * 16 + r) * DMODEL + (col0 + n * 16)] = acc[m][n][r];
}

// ---------------- row softmax: P = softmax(S/32), bf16, in-place ----------------
__global__ __launch_bounds__(256) void softmax_rows(float* __restrict__ S, int N) {
    const int row = blockIdx.x;
    float* s = S + (size_t)row * N;
    const int t = threadIdx.x;

    float v[16];
    float mx = -1e30f;
#pragma unroll
    for (int i = 0; i < 4; ++i) {
        float4 x = reinterpret_cast<const float4*>(s)[t + i * 256];
        v[i * 4 + 0] = x.x;
        v[i * 4 + 1] = x.y;
        v[i * 4 + 2] = x.z;
        v[i * 4 + 3] = x.w;
        mx = fmaxf(mx, fmaxf(fmaxf(x.x, x.y), fmaxf(x.z, x.w)));
    }
#pragma unroll
    for (int off = 32; off; off >>= 1) mx = fmaxf(mx, __shfl_xor(mx, off));
    __shared__ float redm[4];
    if (!(t & 63)) redm[t >> 6] = mx;
    __syncthreads();
    mx = fmaxf(fmaxf(redm[0], redm[1]), fmaxf(redm[2], redm[3]));

    float sum = 0.f;
#pragma unroll
    for (int i = 0; i < 16; ++i) {
        v[i] = __expf((v[i] - mx) * 0.03125f);
        sum += v[i];
    }
#pragma unroll
    for (int off = 32; off; off >>= 1) sum += __shfl_xor(sum, off);
    __shared__ float reds[4];
    if (!(t & 63)) reds[t >> 6] = sum;
    __syncthreads();
    sum = (reds[0] + reds[1]) + (reds[2] + reds[3]);
    const float inv = 1.0f / sum;

    unsigned short* p = reinterpret_cast<unsigned short*>(s);
#pragma unroll
    for (int i = 0; i < 4; ++i) {
        ushort4 o;
        o.x = f32_to_bf16(v[i * 4 + 0] * inv);
        o.y = f32_to_bf16(v[i * 4 + 1] * inv);
        o.z = f32_to_bf16(v[i * 4 + 2] * inv);
        o.w = f32_to_bf16(v[i * 4 + 3] * inv);
        reinterpret_cast<ushort4*>(p)[t + i * 256] = o;
    }
}

extern "C" void kernel_launch(void* const* d_in, const int* in_sizes, int n_in,
                              void* d_out, int out_size, void* d_ws, size_t ws_size,
                              hipStream_t stream) {
    (void)in_sizes; (void)n_in; (void)out_size; (void)ws_size;
    const float* x = (const float*)d_in[0];
    const float* wq = (const float*)d_in[1];
    const float* wk = (const float*)d_in[2];
    const float* wv = (const float*)d_in[3];
    float* out = (float*)d_out;

    // ws layout (MiB): xb 0..8, Wb 8..14 (wq|wk|wv fused, 3072x1024 bf16),
    // QK 14..30 (4096x2048 bf16), Vt 30..38 (1024x4096 bf16),
    // S 38..102 (4096x4096 fp32; P bf16 written in-place over front half of rows)
    const size_t MB = 1ull << 20;
    char* w = (char*)d_ws;
    unsigned short* xb = (unsigned short*)(w + 0 * MB);
    unsigned short* Wb = (unsigned short*)(w + 8 * MB);
    unsigned short* QK = (unsigned short*)(w + 14 * MB);
    unsigned short* Vt = (unsigned short*)(w + 30 * MB);
    float* S           = (float*)(w + 38 * MB);

    cvt_f32_bf16<<<4096, 256, 0, stream>>>(x, xb, (NTOK * DMODEL) / 4);
    cvt_f32_bf16<<<1024, 256, 0, stream>>>(wq, Wb, (DMODEL * DMODEL) / 4);
    cvt_f32_bf16<<<1024, 256, 0, stream>>>(wk, Wb + DMODEL * DMODEL, (DMODEL * DMODEL) / 4);
    cvt_f32_bf16<<<1024, 256, 0, stream>>>(wv, Wb + 2 * DMODEL * DMODEL, (DMODEL * DMODEL) / 4);

    // fused QKV: 768 blocks, XCD-swizzled, 2-phase dbuf
    gemm_qkv<<<768, 256, 0, stream>>>(xb, Wb, QK, Vt);

    // scores: S = Q @ K^T, 1024 blocks, XCD-swizzled, 2-phase dbuf
    gemm_scores<<<1024, 256, 0, stream>>>(QK, S);

    softmax_rows<<<NTOK, 256, 0, stream>>>(S, NTOK);

    // PV: out = P @ Vt^T, 512 blocks (2/CU), 128x64 tile, 2-phase dbuf
    gemm_pv<<<512, 256, 0, stream>>>((const unsigned short*)S, Vt, out);
}